// Round 1
// baseline (4397.404 us; speedup 1.0000x reference)
//
#include <hip/hip_runtime.h>
#include <cfloat>
#include <cstdint>

#define BATCH 2
#define NSEQ 2048
#define CIN 512
#define HEADS 8
#define DIM 64
#define HD 512       // HEADS*DIM
#define QKV3 1536    // 3*HD

// ---------------- GEMM f32: C[M][N] = A[M][K] @ B[K][N] ----------------
// BM=128 BN=64 BK=32, 256 threads, micro-tile 8x4
__global__ __launch_bounds__(256) void gemm_f32_kernel(
    const float* __restrict__ A, const float* __restrict__ B,
    float* __restrict__ C, int M, int N, int K)
{
    __shared__ float As[32][132];  // [k][m], padded to break transpose-store conflicts
    __shared__ float Bs[32][64];   // [k][n]
    const int bm = blockIdx.y * 128;
    const int bn = blockIdx.x * 64;
    const int tid = threadIdx.x;
    const int ty = tid >> 4;   // 0..15 -> m block
    const int tx = tid & 15;   // 0..15 -> n block
    float acc[8][4] = {};
    for (int k0 = 0; k0 < K; k0 += 32) {
        #pragma unroll
        for (int i = 0; i < 4; ++i) {
            int f = tid + i * 256;           // 0..1023 float4s of A tile
            int r = f >> 3, c4 = f & 7;
            const float4 v = *(const float4*)(A + (size_t)(bm + r) * K + k0 + c4 * 4);
            As[c4*4+0][r] = v.x; As[c4*4+1][r] = v.y;
            As[c4*4+2][r] = v.z; As[c4*4+3][r] = v.w;
        }
        #pragma unroll
        for (int i = 0; i < 2; ++i) {
            int f = tid + i * 256;           // 0..511 float4s of B tile
            int r = f >> 4, c4 = f & 15;
            *(float4*)(&Bs[r][c4*4]) =
                *(const float4*)(B + (size_t)(k0 + r) * N + bn + c4 * 4);
        }
        __syncthreads();
        #pragma unroll
        for (int kk = 0; kk < 32; ++kk) {
            float a[8], b[4];
            *(float4*)&a[0] = *(const float4*)(&As[kk][ty*8]);
            *(float4*)&a[4] = *(const float4*)(&As[kk][ty*8+4]);
            *(float4*)&b[0] = *(const float4*)(&Bs[kk][tx*4]);
            #pragma unroll
            for (int i = 0; i < 8; ++i)
                #pragma unroll
                for (int j = 0; j < 4; ++j)
                    acc[i][j] = fmaf(a[i], b[j], acc[i][j]);
        }
        __syncthreads();
    }
    #pragma unroll
    for (int i = 0; i < 8; ++i) {
        float4 v = make_float4(acc[i][0], acc[i][1], acc[i][2], acc[i][3]);
        *(float4*)(C + (size_t)(bm + ty*8 + i) * N + bn + tx*4) = v;
    }
}

// ---------------- scatter qkv_lin -> Q,K,V [B,H,N,D] + l2norm(q,k) ------
// qkv_lin col layout: col = h*192 + d*3 + s   (s = 0:q 1:k 2:v, innermost)
__global__ __launch_bounds__(256) void scatter_norm_kernel(
    const float* __restrict__ qkv, float* __restrict__ Q,
    float* __restrict__ K, float* __restrict__ V)
{
    int gid = blockIdx.x * 256 + threadIdx.x;
    int wid = gid >> 6;            // one wave per (row, h)
    int lane = threadIdx.x & 63;   // = d
    int h = wid & 7;
    int row = wid >> 3;            // b*NSEQ + n
    const float* p = qkv + (size_t)row * QKV3 + h * 192 + lane * 3;
    float q = p[0], k = p[1], v = p[2];
    float nq = q * q, nk = k * k;
    #pragma unroll
    for (int off = 32; off > 0; off >>= 1) {
        nq += __shfl_xor(nq, off);
        nk += __shfl_xor(nk, off);
    }
    float rq = 1.f / fmaxf(sqrtf(nq), 1e-12f);
    float rk = 1.f / fmaxf(sqrtf(nk), 1e-12f);
    int b = row >> 11, n = row & (NSEQ - 1);
    size_t o = (((size_t)(b * HEADS + h)) * NSEQ + n) * DIM + lane;
    Q[o] = q * rq;
    K[o] = k * rk;
    V[o] = v;
}

// ---------------- flash attention f32, TQ=32 x TK=64 --------------------
__global__ __launch_bounds__(256) void attn_kernel(
    const float* __restrict__ Q, const float* __restrict__ K,
    const float* __restrict__ V, const float* __restrict__ bias,
    const float* __restrict__ temp_p, const uint8_t* __restrict__ mask,
    float* __restrict__ Out)
{
    __shared__ float Ks[DIM][66];   // [d][j], padded
    __shared__ float Vs[64][64];    // [j][d]
    __shared__ float Ps[32][66];    // [i][j], padded
    const int bh = blockIdx.y;      // b*HEADS + h
    const int b = bh >> 3, h = bh & 7;
    const int i0 = blockIdx.x * 32;
    const int tid = threadIdx.x;
    const int il = tid >> 3;        // local row 0..31
    const int jb = tid & 7;         // col-block (S) / d-block (PV)
    const float temp = *temp_p;
    const int irow = i0 + il;

    float qreg[DIM];
    {
        const float* qp = Q + ((size_t)bh * NSEQ + irow) * DIM;
        #pragma unroll
        for (int d4 = 0; d4 < 16; ++d4) {
            float4 v = *(const float4*)(qp + d4 * 4);
            qreg[d4*4+0] = v.x; qreg[d4*4+1] = v.y;
            qreg[d4*4+2] = v.z; qreg[d4*4+3] = v.w;
        }
    }
    const bool rowmask = mask[(size_t)b * NSEQ + irow] != 0;
    float m_i = -FLT_MAX, l_i = 0.f;
    float oacc[8] = {0,0,0,0,0,0,0,0};

    for (int j0 = 0; j0 < NSEQ; j0 += 64) {
        __syncthreads();   // previous tile's Ps/Vs fully consumed
        #pragma unroll
        for (int i = 0; i < 4; ++i) {
            int f = tid + i * 256;
            int r = f >> 4, c4 = f & 15;
            const size_t goff = ((size_t)bh * NSEQ + j0 + r) * DIM + c4 * 4;
            float4 kv = *(const float4*)(K + goff);
            Ks[c4*4+0][r] = kv.x; Ks[c4*4+1][r] = kv.y;
            Ks[c4*4+2][r] = kv.z; Ks[c4*4+3][r] = kv.w;
            *(float4*)(&Vs[r][c4*4]) = *(const float4*)(V + goff);
        }
        __syncthreads();

        // S[il][jb*8..+7] = q . k
        float s[8] = {0,0,0,0,0,0,0,0};
        #pragma unroll
        for (int d = 0; d < DIM; ++d) {
            float4 k0v = *(const float4*)(&Ks[d][jb*8]);
            float4 k1v = *(const float4*)(&Ks[d][jb*8+4]);
            s[0] = fmaf(qreg[d], k0v.x, s[0]);
            s[1] = fmaf(qreg[d], k0v.y, s[1]);
            s[2] = fmaf(qreg[d], k0v.z, s[2]);
            s[3] = fmaf(qreg[d], k0v.w, s[3]);
            s[4] = fmaf(qreg[d], k1v.x, s[4]);
            s[5] = fmaf(qreg[d], k1v.y, s[5]);
            s[6] = fmaf(qreg[d], k1v.z, s[6]);
            s[7] = fmaf(qreg[d], k1v.w, s[7]);
        }
        const float* bp = bias + ((size_t)h * NSEQ + irow) * NSEQ + j0 + jb * 8;
        float4 b0 = *(const float4*)bp;
        float4 b1 = *(const float4*)(bp + 4);
        float bb[8] = {b0.x,b0.y,b0.z,b0.w,b1.x,b1.y,b1.z,b1.w};
        const uint8_t* mp = mask + (size_t)b * NSEQ + j0 + jb * 8;
        #pragma unroll
        for (int jj = 0; jj < 8; ++jj) {
            bool dead = rowmask || (mp[jj] != 0);
            s[jj] = dead ? -FLT_MAX : fmaf(s[jj], temp, bb[jj]);
        }
        // online softmax (row = il, 8 lanes share a row)
        float mx = s[0];
        #pragma unroll
        for (int jj = 1; jj < 8; ++jj) mx = fmaxf(mx, s[jj]);
        mx = fmaxf(mx, __shfl_xor(mx, 1));
        mx = fmaxf(mx, __shfl_xor(mx, 2));
        mx = fmaxf(mx, __shfl_xor(mx, 4));
        const float m_new = fmaxf(m_i, mx);
        const float scale = __expf(m_i - m_new);  // (-FLT_MAX)-(-FLT_MAX)=0 -> 1
        float rs = 0.f;
        #pragma unroll
        for (int jj = 0; jj < 8; ++jj) {
            float p = __expf(s[jj] - m_new);
            Ps[il][jb*8+jj] = p;
            rs += p;
        }
        rs += __shfl_xor(rs, 1);
        rs += __shfl_xor(rs, 2);
        rs += __shfl_xor(rs, 4);
        l_i = l_i * scale + rs;
        m_i = m_new;
        #pragma unroll
        for (int dd = 0; dd < 8; ++dd) oacc[dd] *= scale;
        __syncthreads();
        // PV: out[il][jb*8..+7] += P[il][j] * V[j][...]
        #pragma unroll
        for (int j = 0; j < 64; ++j) {
            float p = Ps[il][j];
            float4 v0 = *(const float4*)(&Vs[j][jb*8]);
            float4 v1 = *(const float4*)(&Vs[j][jb*8+4]);
            oacc[0] = fmaf(p, v0.x, oacc[0]);
            oacc[1] = fmaf(p, v0.y, oacc[1]);
            oacc[2] = fmaf(p, v0.z, oacc[2]);
            oacc[3] = fmaf(p, v0.w, oacc[3]);
            oacc[4] = fmaf(p, v1.x, oacc[4]);
            oacc[5] = fmaf(p, v1.y, oacc[5]);
            oacc[6] = fmaf(p, v1.z, oacc[6]);
            oacc[7] = fmaf(p, v1.w, oacc[7]);
        }
    }
    const float inv = 1.f / l_i;
    float* op = Out + ((size_t)b * NSEQ + irow) * HD + h * DIM + jb * 8;
    float4 o0 = make_float4(oacc[0]*inv, oacc[1]*inv, oacc[2]*inv, oacc[3]*inv);
    float4 o1 = make_float4(oacc[4]*inv, oacc[5]*inv, oacc[6]*inv, oacc[7]*inv);
    *(float4*)op = o0;
    *(float4*)(op + 4) = o1;
}

extern "C" void kernel_launch(void* const* d_in, const int* in_sizes, int n_in,
                              void* d_out, int out_size, void* d_ws, size_t ws_size,
                              hipStream_t stream)
{
    const float*   x        = (const float*)d_in[0];
    const float*   w_qkv    = (const float*)d_in[1];
    const float*   w_out    = (const float*)d_in[2];
    const float*   pos_bias = (const float*)d_in[3];
    const float*   temp     = (const float*)d_in[4];
    const uint8_t* mask     = (const uint8_t*)d_in[5];
    float* out = (float*)d_out;

    const int M = BATCH * NSEQ;  // 4096
    char* ws = (char*)d_ws;
    float* qkv_lin = (float*)ws;                                   // M*1536 f32 = 25.2 MB
    float* Qb = (float*)(ws + (size_t)M * QKV3 * 4);               // 8 MB each
    float* Kb = Qb + (size_t)BATCH * HEADS * NSEQ * DIM;
    float* Vb = Kb + (size_t)BATCH * HEADS * NSEQ * DIM;
    float* attn_out = Vb + (size_t)BATCH * HEADS * NSEQ * DIM;     // M*512 f32

    // 1. qkv projection: [4096,512] @ [512,1536]
    gemm_f32_kernel<<<dim3(QKV3 / 64, M / 128), 256, 0, stream>>>(
        x, w_qkv, qkv_lin, M, QKV3, CIN);
    // 2. scatter to [B,H,N,D] + l2norm(q,k)
    scatter_norm_kernel<<<dim3(M * HEADS / 4), 256, 0, stream>>>(
        qkv_lin, Qb, Kb, Vb);
    // 3. fused attention
    attn_kernel<<<dim3(NSEQ / 32, BATCH * HEADS), 256, 0, stream>>>(
        Qb, Kb, Vb, pos_bias, temp, mask, attn_out);
    // 4. out projection: [4096,512] @ [512,512]
    gemm_f32_kernel<<<dim3(CIN / 64, M / 128), 256, 0, stream>>>(
        attn_out, w_out, out, M, CIN, CIN);
}

// Round 2
// 324.098 us; speedup vs baseline: 13.5681x; 13.5681x over previous
//
#include <hip/hip_runtime.h>
#include <cfloat>
#include <cstdint>

#define BATCH 2
#define NSEQ 2048
#define CIN 512
#define HEADS 8
#define DIM 64
#define HD 512       // HEADS*DIM
#define QKV3 1536    // 3*HD

typedef short short8 __attribute__((ext_vector_type(8)));
typedef float f32x4 __attribute__((ext_vector_type(4)));
typedef unsigned short ushort_t;

__device__ __forceinline__ unsigned short f2bf(float f) {
    return (unsigned short)(__float_as_uint(f) >> 16);   // truncate; lo-part catches residual
}
__device__ __forceinline__ float bf2f(unsigned short h) {
    return __uint_as_float(((unsigned int)h) << 16);
}

// ---------------- GEMM f32: C[M][N] = A[M][K] @ B[K][N] ----------------
__global__ __launch_bounds__(256) void gemm_f32_kernel(
    const float* __restrict__ A, const float* __restrict__ B,
    float* __restrict__ C, int M, int N, int K)
{
    __shared__ float As[32][132];
    __shared__ float Bs[32][64];
    const int bm = blockIdx.y * 128;
    const int bn = blockIdx.x * 64;
    const int tid = threadIdx.x;
    const int ty = tid >> 4;
    const int tx = tid & 15;
    float acc[8][4] = {};
    for (int k0 = 0; k0 < K; k0 += 32) {
        #pragma unroll
        for (int i = 0; i < 4; ++i) {
            int f = tid + i * 256;
            int r = f >> 3, c4 = f & 7;
            const float4 v = *(const float4*)(A + (size_t)(bm + r) * K + k0 + c4 * 4);
            As[c4*4+0][r] = v.x; As[c4*4+1][r] = v.y;
            As[c4*4+2][r] = v.z; As[c4*4+3][r] = v.w;
        }
        #pragma unroll
        for (int i = 0; i < 2; ++i) {
            int f = tid + i * 256;
            int r = f >> 4, c4 = f & 15;
            *(float4*)(&Bs[r][c4*4]) =
                *(const float4*)(B + (size_t)(k0 + r) * N + bn + c4 * 4);
        }
        __syncthreads();
        #pragma unroll
        for (int kk = 0; kk < 32; ++kk) {
            float a[8], b[4];
            *(float4*)&a[0] = *(const float4*)(&As[kk][ty*8]);
            *(float4*)&a[4] = *(const float4*)(&As[kk][ty*8+4]);
            *(float4*)&b[0] = *(const float4*)(&Bs[kk][tx*4]);
            #pragma unroll
            for (int i = 0; i < 8; ++i)
                #pragma unroll
                for (int j = 0; j < 4; ++j)
                    acc[i][j] = fmaf(a[i], b[j], acc[i][j]);
        }
        __syncthreads();
    }
    #pragma unroll
    for (int i = 0; i < 8; ++i) {
        float4 v = make_float4(acc[i][0], acc[i][1], acc[i][2], acc[i][3]);
        *(float4*)(C + (size_t)(bm + ty*8 + i) * N + bn + tx*4) = v;
    }
}

// ------- scatter qkv_lin -> Qh/Ql/Kh/Kl bf16 [B,H,N,D], l2norm(q,k) -----
__global__ __launch_bounds__(256) void scatter_norm_kernel(
    const float* __restrict__ qkv,
    ushort_t* __restrict__ Qh, ushort_t* __restrict__ Ql,
    ushort_t* __restrict__ Kh, ushort_t* __restrict__ Kl)
{
    int gid = blockIdx.x * 256 + threadIdx.x;
    int wid = gid >> 6;
    int lane = threadIdx.x & 63;   // = d
    int h = wid & 7;
    int row = wid >> 3;            // b*NSEQ + n
    const float* p = qkv + (size_t)row * QKV3 + h * 192 + lane * 3;
    float q = p[0], k = p[1];
    float nq = q * q, nk = k * k;
    #pragma unroll
    for (int off = 32; off > 0; off >>= 1) {
        nq += __shfl_xor(nq, off);
        nk += __shfl_xor(nk, off);
    }
    float rq = 1.f / fmaxf(sqrtf(nq), 1e-12f);
    float rk = 1.f / fmaxf(sqrtf(nk), 1e-12f);
    q *= rq; k *= rk;
    int b = row >> 11, n = row & (NSEQ - 1);
    size_t o = (((size_t)(b * HEADS + h)) * NSEQ + n) * DIM + lane;
    unsigned short qhi = f2bf(q), khi = f2bf(k);
    Qh[o] = qhi; Ql[o] = f2bf(q - bf2f(qhi));
    Kh[o] = khi; Kl[o] = f2bf(k - bf2f(khi));
}

// ------- V transpose: qkv_lin -> Vt_hi/Vt_lo bf16 [BH][D][N] ------------
__global__ __launch_bounds__(256) void vtrans_kernel(
    const float* __restrict__ qkv,
    ushort_t* __restrict__ Vth, ushort_t* __restrict__ Vtl)
{
    __shared__ ushort_t VhS[64][72], VlS[64][72];  // [d][j]
    const int id = blockIdx.x;          // bh*32 + ntile
    const int bh = id >> 5, nt = id & 31;
    const int b = bh >> 3, h = bh & 7;
    const int n0 = nt * 64;
    const int tid = threadIdx.x;
    {
        int j = tid >> 2, dseg = tid & 3;   // j: 0..63, d = dseg*16+e
        const float* src = qkv + ((size_t)(b * NSEQ + n0 + j)) * QKV3
                         + h * 192 + dseg * 48 + 2;   // v at d*3+2
        #pragma unroll
        for (int e = 0; e < 16; ++e) {
            float v = src[e * 3];
            unsigned short hi = f2bf(v);
            VhS[dseg*16 + e][j] = hi;
            VlS[dseg*16 + e][j] = f2bf(v - bf2f(hi));
        }
    }
    __syncthreads();
    {
        int d = tid >> 2, seg = tid & 3;
        size_t o = ((size_t)(bh * DIM + d)) * NSEQ + n0 + seg * 16;
        *(uint4*)(Vth + o)     = *(const uint4*)(&VhS[d][seg*16]);
        *(uint4*)(Vth + o + 8) = *(const uint4*)(&VhS[d][seg*16 + 8]);
        *(uint4*)(Vtl + o)     = *(const uint4*)(&VlS[d][seg*16]);
        *(uint4*)(Vtl + o + 8) = *(const uint4*)(&VlS[d][seg*16 + 8]);
    }
}

// ---------------- MFMA flash attention, Q-tile 64, KV-tile 64 -----------
__global__ __launch_bounds__(256, 2) void attn_mfma_kernel(
    const ushort_t* __restrict__ Qh, const ushort_t* __restrict__ Ql,
    const ushort_t* __restrict__ Kh, const ushort_t* __restrict__ Kl,
    const ushort_t* __restrict__ Vth, const ushort_t* __restrict__ Vtl,
    const float* __restrict__ bias, const float* __restrict__ temp_p,
    const uint8_t* __restrict__ mask, float* __restrict__ Out)
{
    __shared__ ushort_t KsH[64][72], KsL[64][72];  // [j][d], padded
    __shared__ ushort_t VsH[64][72], VsL[64][72];  // [d][j], padded
    __shared__ float    Ps[4][16][68];             // per-wave P, padded

    // XCD-grouped swizzle: head h -> XCD h; b=0/b=1 twins co-resident
    const int id = blockIdx.x;          // 0..511
    const int h = id & 7;
    const int sub = id >> 3;            // 0..63
    const int b = sub >> 5;
    const int bh = b * 8 + h;
    const int i0 = (sub & 31) * 64;
    const int tid = threadIdx.x;
    const int wave = tid >> 6, lane = tid & 63;
    const int lg = lane >> 4, lm = lane & 15;
    const int qr = i0 + wave * 16;      // wave's 16 q-rows
    const float temp = *temp_p;

    // Q fragments (A-layout: row=lm, k=lg*8+e), hi/lo, two 32-wide k-slices
    short8 qh[2], ql[2];
    {
        size_t qo = ((size_t)(bh * NSEQ + qr + lm)) * DIM + lg * 8;
        qh[0] = *(const short8*)(Qh + qo);
        qh[1] = *(const short8*)(Qh + qo + 32);
        ql[0] = *(const short8*)(Ql + qo);
        ql[1] = *(const short8*)(Ql + qo + 32);
    }
    bool rowm[4];
    #pragma unroll
    for (int r = 0; r < 4; ++r)
        rowm[r] = mask[(size_t)b * NSEQ + qr + lg * 4 + r] != 0;

    float m_r[4] = {-FLT_MAX, -FLT_MAX, -FLT_MAX, -FLT_MAX};
    float l_r[4] = {0.f, 0.f, 0.f, 0.f};
    f32x4 oa[4];
    #pragma unroll
    for (int dt = 0; dt < 4; ++dt) oa[dt] = (f32x4){0.f, 0.f, 0.f, 0.f};

    for (int t = 0; t < NSEQ / 64; ++t) {
        const int j0 = t * 64;
        __syncthreads();   // previous tile fully consumed
        {   // stage K (hi/lo) and Vt (hi/lo) tiles: 32B per thread per array
            const int row = tid >> 2, seg = tid & 3;
            size_t gk = ((size_t)(bh * NSEQ + j0 + row)) * DIM + seg * 16;
            size_t gv = ((size_t)(bh * DIM + row)) * NSEQ + j0 + seg * 16;
            uint4 a0 = *(const uint4*)(Kh + gk);
            uint4 a1 = *(const uint4*)(Kh + gk + 8);
            uint4 b0 = *(const uint4*)(Kl + gk);
            uint4 b1 = *(const uint4*)(Kl + gk + 8);
            uint4 c0 = *(const uint4*)(Vth + gv);
            uint4 c1 = *(const uint4*)(Vth + gv + 8);
            uint4 d0 = *(const uint4*)(Vtl + gv);
            uint4 d1 = *(const uint4*)(Vtl + gv + 8);
            *(uint4*)(&KsH[row][seg*16])     = a0;
            *(uint4*)(&KsH[row][seg*16 + 8]) = a1;
            *(uint4*)(&KsL[row][seg*16])     = b0;
            *(uint4*)(&KsL[row][seg*16 + 8]) = b1;
            *(uint4*)(&VsH[row][seg*16])     = c0;
            *(uint4*)(&VsH[row][seg*16 + 8]) = c1;
            *(uint4*)(&VsL[row][seg*16])     = d0;
            *(uint4*)(&VsL[row][seg*16 + 8]) = d1;
        }
        __syncthreads();

        // ---- S = Q.K^T via split MFMA: hi*hi + hi*lo + lo*hi ----
        f32x4 sac[4];
        #pragma unroll
        for (int jt = 0; jt < 4; ++jt) {
            sac[jt] = (f32x4){0.f, 0.f, 0.f, 0.f};
            #pragma unroll
            for (int ks = 0; ks < 2; ++ks) {
                short8 kbh = *(const short8*)(&KsH[jt*16 + lm][ks*32 + lg*8]);
                short8 kbl = *(const short8*)(&KsL[jt*16 + lm][ks*32 + lg*8]);
                sac[jt] = __builtin_amdgcn_mfma_f32_16x16x32_bf16(qh[ks], kbh, sac[jt], 0, 0, 0);
                sac[jt] = __builtin_amdgcn_mfma_f32_16x16x32_bf16(qh[ks], kbl, sac[jt], 0, 0, 0);
                sac[jt] = __builtin_amdgcn_mfma_f32_16x16x32_bf16(ql[ks], kbh, sac[jt], 0, 0, 0);
            }
        }

        // ---- logits: *temp + bias, masking ----
        float sv[4][4];
        #pragma unroll
        for (int jt = 0; jt < 4; ++jt) {
            const bool cm = mask[(size_t)b * NSEQ + j0 + jt*16 + lm] != 0;
            #pragma unroll
            for (int r = 0; r < 4; ++r) {
                float bv = bias[((size_t)h * NSEQ + qr + lg*4 + r) * NSEQ + j0 + jt*16 + lm];
                bool dead = cm || rowm[r];
                sv[jt][r] = dead ? -FLT_MAX : fmaf(sac[jt][r], temp, bv);
            }
        }

        // ---- online softmax (rows live in 16-lane groups) ----
        float scl[4], rs[4];
        #pragma unroll
        for (int r = 0; r < 4; ++r) {
            float m0 = fmaxf(fmaxf(sv[0][r], sv[1][r]), fmaxf(sv[2][r], sv[3][r]));
            m0 = fmaxf(m0, __shfl_xor(m0, 1));
            m0 = fmaxf(m0, __shfl_xor(m0, 2));
            m0 = fmaxf(m0, __shfl_xor(m0, 4));
            m0 = fmaxf(m0, __shfl_xor(m0, 8));
            float mn = fmaxf(m_r[r], m0);
            scl[r] = __expf(m_r[r] - mn);
            m_r[r] = mn;
            rs[r] = 0.f;
        }
        #pragma unroll
        for (int jt = 0; jt < 4; ++jt)
            #pragma unroll
            for (int r = 0; r < 4; ++r) {
                float p = __expf(sv[jt][r] - m_r[r]);
                Ps[wave][lg*4 + r][jt*16 + lm] = p;
                rs[r] += p;
            }
        #pragma unroll
        for (int r = 0; r < 4; ++r) {
            rs[r] += __shfl_xor(rs[r], 1);
            rs[r] += __shfl_xor(rs[r], 2);
            rs[r] += __shfl_xor(rs[r], 4);
            rs[r] += __shfl_xor(rs[r], 8);
            l_r[r] = l_r[r] * scl[r] + rs[r];
        }
        #pragma unroll
        for (int dt = 0; dt < 4; ++dt) {
            oa[dt][0] *= scl[0]; oa[dt][1] *= scl[1];
            oa[dt][2] *= scl[2]; oa[dt][3] *= scl[3];
        }

        // wave-local Ps write->read ordering (DS ops in-order per wave)
        asm volatile("s_waitcnt lgkmcnt(0)" ::: "memory");

        // ---- O += P.V via split MFMA: Ph*Vh + Pl*Vh + Ph*Vl ----
        #pragma unroll
        for (int ks = 0; ks < 2; ++ks) {
            f32x4 p0 = *(const f32x4*)(&Ps[wave][lm][ks*32 + lg*8]);
            f32x4 p1 = *(const f32x4*)(&Ps[wave][lm][ks*32 + lg*8 + 4]);
            short8 ph, pl;
            #pragma unroll
            for (int e = 0; e < 4; ++e) {
                unsigned short h0 = f2bf(p0[e]);
                ph[e]   = (short)h0;
                pl[e]   = (short)f2bf(p0[e] - bf2f(h0));
                unsigned short h1 = f2bf(p1[e]);
                ph[e+4] = (short)h1;
                pl[e+4] = (short)f2bf(p1[e] - bf2f(h1));
            }
            #pragma unroll
            for (int dt = 0; dt < 4; ++dt) {
                short8 vbh = *(const short8*)(&VsH[dt*16 + lm][ks*32 + lg*8]);
                short8 vbl = *(const short8*)(&VsL[dt*16 + lm][ks*32 + lg*8]);
                oa[dt] = __builtin_amdgcn_mfma_f32_16x16x32_bf16(ph, vbh, oa[dt], 0, 0, 0);
                oa[dt] = __builtin_amdgcn_mfma_f32_16x16x32_bf16(pl, vbh, oa[dt], 0, 0, 0);
                oa[dt] = __builtin_amdgcn_mfma_f32_16x16x32_bf16(ph, vbl, oa[dt], 0, 0, 0);
            }
        }
    }

    // ---- epilogue: divide by l, write [B,N,H*D] ----
    #pragma unroll
    for (int dt = 0; dt < 4; ++dt)
        #pragma unroll
        for (int r = 0; r < 4; ++r) {
            float o = oa[dt][r] / l_r[r];
            Out[((size_t)(b * NSEQ + qr + lg*4 + r)) * HD + h * DIM + dt*16 + lm] = o;
        }
}

extern "C" void kernel_launch(void* const* d_in, const int* in_sizes, int n_in,
                              void* d_out, int out_size, void* d_ws, size_t ws_size,
                              hipStream_t stream)
{
    const float*   x        = (const float*)d_in[0];
    const float*   w_qkv    = (const float*)d_in[1];
    const float*   w_out    = (const float*)d_in[2];
    const float*   pos_bias = (const float*)d_in[3];
    const float*   temp     = (const float*)d_in[4];
    const uint8_t* mask     = (const uint8_t*)d_in[5];
    float* out = (float*)d_out;

    const int M = BATCH * NSEQ;  // 4096
    const size_t NE = (size_t)BATCH * HEADS * NSEQ * DIM;  // 2M elements
    char* ws = (char*)d_ws;
    float* qkv_lin = (float*)ws;                          // 25.2 MB
    size_t off = (size_t)M * QKV3 * 4;
    ushort_t* Qh  = (ushort_t*)(ws + off); off += NE * 2; // 4 MB each
    ushort_t* Ql  = (ushort_t*)(ws + off); off += NE * 2;
    ushort_t* Kh  = (ushort_t*)(ws + off); off += NE * 2;
    ushort_t* Kl  = (ushort_t*)(ws + off); off += NE * 2;
    ushort_t* Vth = (ushort_t*)(ws + off); off += NE * 2;
    ushort_t* Vtl = (ushort_t*)(ws + off); off += NE * 2;
    float* attn_out = (float*)(ws + off);                 // 8 MB

    // 1. qkv projection
    gemm_f32_kernel<<<dim3(QKV3 / 64, M / 128), 256, 0, stream>>>(
        x, w_qkv, qkv_lin, M, QKV3, CIN);
    // 2. l2norm + bf16 hi/lo split for Q,K
    scatter_norm_kernel<<<dim3(M * HEADS / 4), 256, 0, stream>>>(
        qkv_lin, Qh, Ql, Kh, Kl);
    // 3. V transpose to [BH][D][N] bf16 hi/lo
    vtrans_kernel<<<dim3(BATCH * HEADS * (NSEQ / 64)), 256, 0, stream>>>(
        qkv_lin, Vth, Vtl);
    // 4. MFMA flash attention
    attn_mfma_kernel<<<dim3(BATCH * HEADS * (NSEQ / 64)), 256, 0, stream>>>(
        Qh, Ql, Kh, Kl, Vth, Vtl, pos_bias, temp, mask, attn_out);
    // 5. out projection
    gemm_f32_kernel<<<dim3(CIN / 64, M / 128), 256, 0, stream>>>(
        attn_out, w_out, out, M, CIN, CIN);
}

// Round 3
// 223.499 us; speedup vs baseline: 19.6753x; 1.4501x over previous
//
#include <hip/hip_runtime.h>
#include <cfloat>
#include <cstdint>

#define BATCH 2
#define NSEQ 2048
#define CIN 512
#define HEADS 8
#define DIM 64
#define HD 512
#define QKV3 1536

typedef short short8 __attribute__((ext_vector_type(8)));
typedef float f32x4 __attribute__((ext_vector_type(4)));
typedef unsigned short ushort_t;

__device__ __forceinline__ unsigned short f2bf(float f) {
    return (unsigned short)(__float_as_uint(f) >> 16);
}
__device__ __forceinline__ float bf2f(unsigned short h) {
    return __uint_as_float(((unsigned int)h) << 16);
}

// ---------- split + transpose weights: W[K][N] f32 -> WT[N][K] bf16 hi/lo ----
__global__ __launch_bounds__(256) void split_wT_kernel(
    const float* __restrict__ W, ushort_t* __restrict__ WTh,
    ushort_t* __restrict__ WTl, int K, int N)
{
    __shared__ float T[64][65];
    const int k0 = blockIdx.y * 64, n0 = blockIdx.x * 64;
    const int tid = threadIdx.x;
    #pragma unroll
    for (int i = 0; i < 4; ++i) {
        int c = tid + i * 256;
        int row = c >> 4, c4 = c & 15;
        *(float4*)&T[row][c4*4] = *(const float4*)(W + (size_t)(k0 + row) * N + n0 + c4*4);
    }
    __syncthreads();
    const int n = tid >> 2, kseg = tid & 3;
    short8 hh0, ll0, hh1, ll1;
    #pragma unroll
    for (int e = 0; e < 8; ++e) {
        float x0 = T[kseg*16 + e][n];
        unsigned short h0 = f2bf(x0);
        hh0[e] = (short)h0; ll0[e] = (short)f2bf(x0 - bf2f(h0));
        float x1 = T[kseg*16 + 8 + e][n];
        unsigned short h1 = f2bf(x1);
        hh1[e] = (short)h1; ll1[e] = (short)f2bf(x1 - bf2f(h1));
    }
    size_t o = (size_t)(n0 + n) * K + k0 + kseg * 16;
    *(short8*)(WTh + o)     = hh0;
    *(short8*)(WTh + o + 8) = hh1;
    *(short8*)(WTl + o)     = ll0;
    *(short8*)(WTl + o + 8) = ll1;
}

// ---------- split-bf16 MFMA GEMM: C[M][N] = A[M][K](f32) @ BT[N][K](bf16 h/l) --
// BM=128 BN=64 BK=64, 256 thr (4 waves), wave-tile 64x32
__global__ __launch_bounds__(256, 2) void gemm_split_kernel(
    const float* __restrict__ A, const ushort_t* __restrict__ BTh,
    const ushort_t* __restrict__ BTl, float* __restrict__ C,
    int M, int N, int K)
{
    __shared__ ushort_t Ash[128][72], Asl[128][72];
    __shared__ ushort_t Bsh[64][72],  Bsl[64][72];
    const int bm = blockIdx.y * 128, bn = blockIdx.x * 64;
    const int tid = threadIdx.x;
    const int wave = tid >> 6, lane = tid & 63;
    const int lg = lane >> 4, lm = lane & 15;
    const int wm = wave >> 1, wn = wave & 1;
    const int arow = tid >> 3, aseg = tid & 7;   // +32*i rows

    f32x4 acc[4][2];
    #pragma unroll
    for (int mf = 0; mf < 4; ++mf)
        #pragma unroll
        for (int nf = 0; nf < 2; ++nf) acc[mf][nf] = (f32x4){0.f,0.f,0.f,0.f};

    float4 ar[8];
    uint4 brh[2], brl[2];
    const int nkt = K >> 6;

    #define G_ISSUE(K0)                                                          \
        { _Pragma("unroll")                                                      \
          for (int i = 0; i < 4; ++i) {                                          \
            const float* ap = A + (size_t)(bm + arow + 32*i) * K + (K0) + aseg*8;\
            ar[2*i]   = *(const float4*)ap;                                      \
            ar[2*i+1] = *(const float4*)(ap + 4);                                \
          }                                                                      \
          _Pragma("unroll")                                                      \
          for (int i = 0; i < 2; ++i) {                                          \
            size_t bo = (size_t)(bn + arow + 32*i) * K + (K0) + aseg*8;          \
            brh[i] = *(const uint4*)(BTh + bo);                                  \
            brl[i] = *(const uint4*)(BTl + bo);                                  \
          } }

    G_ISSUE(0)
    for (int kt = 0; kt < nkt; ++kt) {
        __syncthreads();
        #pragma unroll
        for (int i = 0; i < 4; ++i) {
            float av[8];
            *(float4*)&av[0] = ar[2*i];
            *(float4*)&av[4] = ar[2*i+1];
            short8 hh, ll;
            #pragma unroll
            for (int e = 0; e < 8; ++e) {
                unsigned short hi = f2bf(av[e]);
                hh[e] = (short)hi;
                ll[e] = (short)f2bf(av[e] - bf2f(hi));
            }
            *(short8*)&Ash[arow + 32*i][aseg*8] = hh;
            *(short8*)&Asl[arow + 32*i][aseg*8] = ll;
        }
        #pragma unroll
        for (int i = 0; i < 2; ++i) {
            *(uint4*)&Bsh[arow + 32*i][aseg*8] = brh[i];
            *(uint4*)&Bsl[arow + 32*i][aseg*8] = brl[i];
        }
        if (kt + 1 < nkt) G_ISSUE((kt + 1) * 64)
        __syncthreads();
        #pragma unroll
        for (int ks = 0; ks < 2; ++ks) {
            short8 afh[4], afl[4], bfh[2], bfl[2];
            #pragma unroll
            for (int mf = 0; mf < 4; ++mf) {
                afh[mf] = *(const short8*)&Ash[wm*64 + mf*16 + lm][ks*32 + lg*8];
                afl[mf] = *(const short8*)&Asl[wm*64 + mf*16 + lm][ks*32 + lg*8];
            }
            #pragma unroll
            for (int nf = 0; nf < 2; ++nf) {
                bfh[nf] = *(const short8*)&Bsh[wn*32 + nf*16 + lm][ks*32 + lg*8];
                bfl[nf] = *(const short8*)&Bsl[wn*32 + nf*16 + lm][ks*32 + lg*8];
            }
            #pragma unroll
            for (int mf = 0; mf < 4; ++mf)
                #pragma unroll
                for (int nf = 0; nf < 2; ++nf) {
                    acc[mf][nf] = __builtin_amdgcn_mfma_f32_16x16x32_bf16(afh[mf], bfh[nf], acc[mf][nf], 0, 0, 0);
                    acc[mf][nf] = __builtin_amdgcn_mfma_f32_16x16x32_bf16(afh[mf], bfl[nf], acc[mf][nf], 0, 0, 0);
                    acc[mf][nf] = __builtin_amdgcn_mfma_f32_16x16x32_bf16(afl[mf], bfh[nf], acc[mf][nf], 0, 0, 0);
                }
        }
    }
    #pragma unroll
    for (int mf = 0; mf < 4; ++mf)
        #pragma unroll
        for (int nf = 0; nf < 2; ++nf)
            #pragma unroll
            for (int r = 0; r < 4; ++r)
                C[(size_t)(bm + wm*64 + mf*16 + lg*4 + r) * N + bn + wn*32 + nf*16 + lm]
                    = acc[mf][nf][r];
    #undef G_ISSUE
}

// ------- scatter qkv_lin -> Qh/Ql/Kh/Kl bf16 [B,H,N,D], l2norm(q,k) -----
__global__ __launch_bounds__(256) void scatter_norm_kernel(
    const float* __restrict__ qkv,
    ushort_t* __restrict__ Qh, ushort_t* __restrict__ Ql,
    ushort_t* __restrict__ Kh, ushort_t* __restrict__ Kl)
{
    int gid = blockIdx.x * 256 + threadIdx.x;
    int wid = gid >> 6;
    int lane = threadIdx.x & 63;
    int h = wid & 7;
    int row = wid >> 3;
    const float* p = qkv + (size_t)row * QKV3 + h * 192 + lane * 3;
    float q = p[0], k = p[1];
    float nq = q * q, nk = k * k;
    #pragma unroll
    for (int off = 32; off > 0; off >>= 1) {
        nq += __shfl_xor(nq, off);
        nk += __shfl_xor(nk, off);
    }
    float rq = 1.f / fmaxf(sqrtf(nq), 1e-12f);
    float rk = 1.f / fmaxf(sqrtf(nk), 1e-12f);
    q *= rq; k *= rk;
    int b = row >> 11, n = row & (NSEQ - 1);
    size_t o = (((size_t)(b * HEADS + h)) * NSEQ + n) * DIM + lane;
    unsigned short qhi = f2bf(q), khi = f2bf(k);
    Qh[o] = qhi; Ql[o] = f2bf(q - bf2f(qhi));
    Kh[o] = khi; Kl[o] = f2bf(k - bf2f(khi));
}

// ------- V transpose: qkv_lin -> Vt_hi/Vt_lo bf16 [BH][D][N] ------------
__global__ __launch_bounds__(256) void vtrans_kernel(
    const float* __restrict__ qkv,
    ushort_t* __restrict__ Vth, ushort_t* __restrict__ Vtl)
{
    __shared__ ushort_t VhS[64][72], VlS[64][72];
    const int id = blockIdx.x;
    const int bh = id >> 5, nt = id & 31;
    const int b = bh >> 3, h = bh & 7;
    const int n0 = nt * 64;
    const int tid = threadIdx.x;
    {
        int j = tid >> 2, dseg = tid & 3;
        const float* src = qkv + ((size_t)(b * NSEQ + n0 + j)) * QKV3
                         + h * 192 + dseg * 48 + 2;
        #pragma unroll
        for (int e = 0; e < 16; ++e) {
            float v = src[e * 3];
            unsigned short hi = f2bf(v);
            VhS[dseg*16 + e][j] = hi;
            VlS[dseg*16 + e][j] = f2bf(v - bf2f(hi));
        }
    }
    __syncthreads();
    {
        int d = tid >> 2, seg = tid & 3;
        size_t o = ((size_t)(bh * DIM + d)) * NSEQ + n0 + seg * 16;
        *(uint4*)(Vth + o)     = *(const uint4*)(&VhS[d][seg*16]);
        *(uint4*)(Vth + o + 8) = *(const uint4*)(&VhS[d][seg*16 + 8]);
        *(uint4*)(Vtl + o)     = *(const uint4*)(&VlS[d][seg*16]);
        *(uint4*)(Vtl + o + 8) = *(const uint4*)(&VlS[d][seg*16 + 8]);
    }
}

// ---------------- MFMA flash attention v3 --------------------------------
// Q-tile 128 (4 waves x 32 rows), KV-tile 64, j-split 2, grid 512
__global__ __launch_bounds__(256, 2) void attn_mfma_kernel(
    const ushort_t* __restrict__ Qh, const ushort_t* __restrict__ Ql,
    const ushort_t* __restrict__ Kh, const ushort_t* __restrict__ Kl,
    const ushort_t* __restrict__ Vth, const ushort_t* __restrict__ Vtl,
    const float* __restrict__ bias, const float* __restrict__ temp_p,
    const uint8_t* __restrict__ mask, float* __restrict__ Opart,
    float* __restrict__ Ml)
{
    __shared__ ushort_t KsH[64][72], KsL[64][72];   // [j][d]
    __shared__ ushort_t VsH[64][72], VsL[64][72];   // [d][j]
    __shared__ unsigned int Ps[4][32][68];          // packed P hi|lo per wave

    const int id = blockIdx.x;
    const int h = id & 7;                 // XCD-grouped
    const int rest = id >> 3;             // 0..63
    const int js = rest & 1;
    const int qt = (rest >> 1) & 15;
    const int b = rest >> 5;
    const int bh = b * 8 + h;
    const int i0 = qt * 128;
    const int tid = threadIdx.x;
    const int wave = tid >> 6, lane = tid & 63;
    const int lg = lane >> 4, lm = lane & 15;
    const int qbase = i0 + wave * 32;
    const float temp = *temp_p;
    const int srow = tid >> 3, sseg = tid & 7;   // staging: rows srow, srow+32

    // Q fragments: 2 m-frags x 2 k-slices, hi/lo
    short8 qh[2][2], ql[2][2];
    #pragma unroll
    for (int m = 0; m < 2; ++m) {
        size_t qo = ((size_t)(bh * NSEQ + qbase + 16*m + lm)) * DIM + lg * 8;
        qh[m][0] = *(const short8*)(Qh + qo);
        qh[m][1] = *(const short8*)(Qh + qo + 32);
        ql[m][0] = *(const short8*)(Ql + qo);
        ql[m][1] = *(const short8*)(Ql + qo + 32);
    }
    bool rowm[2][4];
    #pragma unroll
    for (int m = 0; m < 2; ++m)
        #pragma unroll
        for (int r = 0; r < 4; ++r)
            rowm[m][r] = mask[(size_t)b * NSEQ + qbase + 16*m + lg*4 + r] != 0;

    float m_r[2][4], l_r[2][4];
    f32x4 oa[2][4];
    #pragma unroll
    for (int m = 0; m < 2; ++m)
        #pragma unroll
        for (int r = 0; r < 4; ++r) { m_r[m][r] = -FLT_MAX; l_r[m][r] = 0.f; }
    #pragma unroll
    for (int m = 0; m < 2; ++m)
        #pragma unroll
        for (int dt = 0; dt < 4; ++dt) oa[m][dt] = (f32x4){0.f,0.f,0.f,0.f};

    uint4 skh[2], skl[2], svh[2], svl[2];
    const int NT = (NSEQ / 2) / 64;   // 16 tiles per j-half

    #define A_ISSUE(J0)                                                           \
        { _Pragma("unroll")                                                       \
          for (int i = 0; i < 2; ++i) {                                           \
            size_t gk = ((size_t)(bh * NSEQ) + (J0) + srow + 32*i) * DIM + sseg*8;\
            size_t gv = ((size_t)(bh * DIM)  + srow + 32*i) * NSEQ + (J0) + sseg*8;\
            skh[i] = *(const uint4*)(Kh  + gk);                                   \
            skl[i] = *(const uint4*)(Kl  + gk);                                   \
            svh[i] = *(const uint4*)(Vth + gv);                                   \
            svl[i] = *(const uint4*)(Vtl + gv);                                   \
          } }

    A_ISSUE(js * (NSEQ/2))
    #pragma unroll 1
    for (int t = 0; t < NT; ++t) {
        const int j0 = js * (NSEQ/2) + t * 64;
        __syncthreads();
        #pragma unroll
        for (int i = 0; i < 2; ++i) {
            *(uint4*)&KsH[srow + 32*i][sseg*8] = skh[i];
            *(uint4*)&KsL[srow + 32*i][sseg*8] = skl[i];
            *(uint4*)&VsH[srow + 32*i][sseg*8] = svh[i];
            *(uint4*)&VsL[srow + 32*i][sseg*8] = svl[i];
        }
        if (t + 1 < NT) A_ISSUE(j0 + 64)
        __syncthreads();

        // prefetch bias + col mask early (consumed after QK^T)
        float bb[2][4][4];
        #pragma unroll
        for (int m = 0; m < 2; ++m)
            #pragma unroll
            for (int jt = 0; jt < 4; ++jt)
                #pragma unroll
                for (int r = 0; r < 4; ++r)
                    bb[m][jt][r] = bias[((size_t)h * NSEQ + qbase + 16*m + lg*4 + r) * NSEQ
                                        + j0 + jt*16 + lm];
        bool cm[4];
        #pragma unroll
        for (int jt = 0; jt < 4; ++jt)
            cm[jt] = mask[(size_t)b * NSEQ + j0 + jt*16 + lm] != 0;

        // ---- QK^T ----
        f32x4 sac[2][4];
        #pragma unroll
        for (int m = 0; m < 2; ++m)
            #pragma unroll
            for (int jt = 0; jt < 4; ++jt) sac[m][jt] = (f32x4){0.f,0.f,0.f,0.f};
        #pragma unroll
        for (int jt = 0; jt < 4; ++jt)
            #pragma unroll
            for (int ks = 0; ks < 2; ++ks) {
                short8 kbh = *(const short8*)(&KsH[jt*16 + lm][ks*32 + lg*8]);
                short8 kbl = *(const short8*)(&KsL[jt*16 + lm][ks*32 + lg*8]);
                #pragma unroll
                for (int m = 0; m < 2; ++m) {
                    sac[m][jt] = __builtin_amdgcn_mfma_f32_16x16x32_bf16(qh[m][ks], kbh, sac[m][jt], 0, 0, 0);
                    sac[m][jt] = __builtin_amdgcn_mfma_f32_16x16x32_bf16(qh[m][ks], kbl, sac[m][jt], 0, 0, 0);
                    sac[m][jt] = __builtin_amdgcn_mfma_f32_16x16x32_bf16(ql[m][ks], kbh, sac[m][jt], 0, 0, 0);
                }
            }

        // ---- logits + online softmax ----
        float scl[2][4];
        #pragma unroll
        for (int m = 0; m < 2; ++m) {
            float sv[4][4];
            #pragma unroll
            for (int jt = 0; jt < 4; ++jt)
                #pragma unroll
                for (int r = 0; r < 4; ++r) {
                    bool dead = cm[jt] || rowm[m][r];
                    sv[jt][r] = dead ? -FLT_MAX : fmaf(sac[m][jt][r], temp, bb[m][jt][r]);
                }
            #pragma unroll
            for (int r = 0; r < 4; ++r) {
                float m0 = fmaxf(fmaxf(sv[0][r], sv[1][r]), fmaxf(sv[2][r], sv[3][r]));
                m0 = fmaxf(m0, __shfl_xor(m0, 1));
                m0 = fmaxf(m0, __shfl_xor(m0, 2));
                m0 = fmaxf(m0, __shfl_xor(m0, 4));
                m0 = fmaxf(m0, __shfl_xor(m0, 8));
                float mn = fmaxf(m_r[m][r], m0);
                scl[m][r] = __expf(m_r[m][r] - mn);
                m_r[m][r] = mn;
                float rs = 0.f;
                #pragma unroll
                for (int jt = 0; jt < 4; ++jt) {
                    float p = __expf(sv[jt][r] - mn);
                    unsigned short ph = f2bf(p);
                    unsigned short pl = f2bf(p - bf2f(ph));
                    Ps[wave][16*m + lg*4 + r][jt*16 + lm] = ((unsigned int)ph << 16) | pl;
                    rs += p;
                }
                rs += __shfl_xor(rs, 1);
                rs += __shfl_xor(rs, 2);
                rs += __shfl_xor(rs, 4);
                rs += __shfl_xor(rs, 8);
                l_r[m][r] = l_r[m][r] * scl[m][r] + rs;
            }
        }
        #pragma unroll
        for (int m = 0; m < 2; ++m)
            #pragma unroll
            for (int dt = 0; dt < 4; ++dt) {
                oa[m][dt][0] *= scl[m][0]; oa[m][dt][1] *= scl[m][1];
                oa[m][dt][2] *= scl[m][2]; oa[m][dt][3] *= scl[m][3];
            }

        asm volatile("s_waitcnt lgkmcnt(0)" ::: "memory");

        // ---- PV ----
        #pragma unroll
        for (int ks = 0; ks < 2; ++ks) {
            short8 vbh[4], vbl[4];
            #pragma unroll
            for (int dt = 0; dt < 4; ++dt) {
                vbh[dt] = *(const short8*)(&VsH[dt*16 + lm][ks*32 + lg*8]);
                vbl[dt] = *(const short8*)(&VsL[dt*16 + lm][ks*32 + lg*8]);
            }
            #pragma unroll
            for (int m = 0; m < 2; ++m) {
                unsigned int pu[8];
                *(uint4*)&pu[0] = *(const uint4*)(&Ps[wave][16*m + lm][ks*32 + lg*8]);
                *(uint4*)&pu[4] = *(const uint4*)(&Ps[wave][16*m + lm][ks*32 + lg*8 + 4]);
                short8 ph, pl;
                #pragma unroll
                for (int e = 0; e < 8; ++e) {
                    ph[e] = (short)(pu[e] >> 16);
                    pl[e] = (short)(pu[e] & 0xFFFF);
                }
                #pragma unroll
                for (int dt = 0; dt < 4; ++dt) {
                    oa[m][dt] = __builtin_amdgcn_mfma_f32_16x16x32_bf16(ph, vbh[dt], oa[m][dt], 0, 0, 0);
                    oa[m][dt] = __builtin_amdgcn_mfma_f32_16x16x32_bf16(pl, vbh[dt], oa[m][dt], 0, 0, 0);
                    oa[m][dt] = __builtin_amdgcn_mfma_f32_16x16x32_bf16(ph, vbl[dt], oa[m][dt], 0, 0, 0);
                }
            }
        }
    }
    #undef A_ISSUE

    // ---- epilogue: unnormalized partials + (m,l) ----
    #pragma unroll
    for (int m = 0; m < 2; ++m)
        #pragma unroll
        for (int dt = 0; dt < 4; ++dt)
            #pragma unroll
            for (int r = 0; r < 4; ++r)
                Opart[((size_t)(js*16 + bh) * NSEQ + qbase + 16*m + lg*4 + r) * 64
                      + dt*16 + lm] = oa[m][dt][r];
    if (lm == 0) {
        #pragma unroll
        for (int m = 0; m < 2; ++m)
            #pragma unroll
            for (int r = 0; r < 4; ++r) {
                size_t mi = ((size_t)(js*16 + bh) * NSEQ + qbase + 16*m + lg*4 + r) * 2;
                Ml[mi]     = m_r[m][r];
                Ml[mi + 1] = l_r[m][r];
            }
    }
}

// ---------------- merge the 2 j-split partials -> AO f32 [M][HD] --------
__global__ __launch_bounds__(256) void merge_kernel(
    const float* __restrict__ Opart, const float* __restrict__ Ml,
    float* __restrict__ AO)
{
    int row = blockIdx.x * 4 + (threadIdx.x >> 6);
    int d = threadIdx.x & 63;
    int bh = row >> 11, n = row & (NSEQ - 1);
    int b = bh >> 3, h = bh & 7;
    size_t i1 = (size_t)bh * NSEQ + n;
    size_t i2 = (size_t)(16 + bh) * NSEQ + n;
    float m1 = Ml[i1*2], l1 = Ml[i1*2 + 1];
    float m2 = Ml[i2*2], l2 = Ml[i2*2 + 1];
    float mm = fmaxf(m1, m2);
    float w1 = __expf(m1 - mm), w2 = __expf(m2 - mm);
    float l = l1 * w1 + l2 * w2;
    float o = (Opart[i1*64 + d] * w1 + Opart[i2*64 + d] * w2) / l;
    AO[((size_t)(b * NSEQ + n)) * HD + h * DIM + d] = o;
}

extern "C" void kernel_launch(void* const* d_in, const int* in_sizes, int n_in,
                              void* d_out, int out_size, void* d_ws, size_t ws_size,
                              hipStream_t stream)
{
    const float*   x        = (const float*)d_in[0];
    const float*   w_qkv    = (const float*)d_in[1];
    const float*   w_out    = (const float*)d_in[2];
    const float*   pos_bias = (const float*)d_in[3];
    const float*   temp     = (const float*)d_in[4];
    const uint8_t* mask     = (const uint8_t*)d_in[5];
    float* out = (float*)d_out;

    const int M = BATCH * NSEQ;                        // 4096
    const size_t NE = (size_t)BATCH * HEADS * NSEQ * DIM;
    char* ws = (char*)d_ws;

    // region 0: qkv_lin f32 (25.2 MB), later reused for Opart + Ml
    float* qkv_lin = (float*)ws;
    float* OpartP  = (float*)ws;                                   // 16.8 MB
    float* MlP     = (float*)(ws + (size_t)2*16*NSEQ*64*4);        // 1 MB
    size_t off = (size_t)M * QKV3 * 4;
    // region 1: transposed/split weights (persistent)
    ushort_t* WqkvTh = (ushort_t*)(ws + off); off += (size_t)QKV3 * CIN * 2;
    ushort_t* WqkvTl = (ushort_t*)(ws + off); off += (size_t)QKV3 * CIN * 2;
    ushort_t* WoutTh = (ushort_t*)(ws + off); off += (size_t)HD * CIN * 2;
    ushort_t* WoutTl = (ushort_t*)(ws + off); off += (size_t)HD * CIN * 2;
    // region 2: Q/K hi-lo + Vt hi-lo; AO reuses this after attention
    char* reg2 = ws + off;
    ushort_t* Qh  = (ushort_t*)reg2;
    ushort_t* Ql  = Qh + NE;
    ushort_t* Kh  = Ql + NE;
    ushort_t* Kl  = Kh + NE;
    ushort_t* Vth = Kl + NE;
    ushort_t* Vtl = Vth + NE;
    float* AO = (float*)reg2;   // 8 MB, overlaps dead Qh/Ql after attention

    // 1. weight split+transpose
    split_wT_kernel<<<dim3(QKV3/64, CIN/64), 256, 0, stream>>>(w_qkv, WqkvTh, WqkvTl, CIN, QKV3);
    split_wT_kernel<<<dim3(HD/64,  CIN/64), 256, 0, stream>>>(w_out, WoutTh, WoutTl, CIN, HD);
    // 2. qkv projection (MFMA split)
    gemm_split_kernel<<<dim3(QKV3/64, M/128), 256, 0, stream>>>(
        x, WqkvTh, WqkvTl, qkv_lin, M, QKV3, CIN);
    // 3. l2norm + bf16 hi/lo split Q,K
    scatter_norm_kernel<<<dim3(M * HEADS / 4), 256, 0, stream>>>(qkv_lin, Qh, Ql, Kh, Kl);
    // 4. V transpose
    vtrans_kernel<<<dim3(BATCH * HEADS * (NSEQ/64)), 256, 0, stream>>>(qkv_lin, Vth, Vtl);
    // 5. attention (j-split 2)
    attn_mfma_kernel<<<dim3(512), 256, 0, stream>>>(
        Qh, Ql, Kh, Kl, Vth, Vtl, pos_bias, temp, mask, OpartP, MlP);
    // 6. merge partials
    merge_kernel<<<dim3(M * HEADS / 4), 256, 0, stream>>>(OpartP, MlP, AO);
    // 7. out projection (MFMA split)
    gemm_split_kernel<<<dim3(HD/64, M/128), 256, 0, stream>>>(
        AO, WoutTh, WoutTl, out, M, HD, CIN);
}